// Round 4
// baseline (124.785 us; speedup 1.0000x reference)
//
#include <hip/hip_runtime.h>
#include <math.h>

#define NCOLS 5000
#define NF4   1250            // NCOLS / 4
#define QBLK  4               // quarter-blocks per row
#define QF4   313             // ceil(NF4 / QBLK); last quarter has 311
#define BLOCK 256
#define NWAVES (BLOCK / 64)
#define TOPKK 10
#define TR    3               // threshold rounds per wave (4 waves * 3 >= 12 >= k)
#define CAP   64              // padded candidate slots per quarter per path

// ---- ws float layout (nrq = nrows*QBLK):
//   sums : [nrq][8]        (nv, sq, sp, seyy, seyu, aspu, aspd, pad)
//   top  : [nrq][CAP]      float2 (key bits, u value), zero-padded
//   bot  : [nrq][CAP]      float2 (key bits, d value), zero-padded
// total = nrq*(8 + 4*CAP)*4 B  ~= 4.3 MB for nrows=1024

// Monotone-ascending mapping float -> uint32 (total order on finite floats).
__device__ __forceinline__ unsigned mono_f32(float f) {
  unsigned u = __float_as_uint(f);
  return (u & 0x80000000u) ? ~u : (u | 0x80000000u);
}

__device__ __forceinline__ float wave_sum_f(float v) {
#pragma unroll
  for (int o = 1; o < 64; o <<= 1) v += __shfl_xor(v, o);
  return v;
}
__device__ __forceinline__ int wave_sum_i(int v) {
#pragma unroll
  for (int o = 1; o < 64; o <<= 1) v += __shfl_xor(v, o);
  return v;
}
__device__ __forceinline__ unsigned wave_max_u(unsigned v) {
#pragma unroll
  for (int o = 1; o < 64; o <<= 1) {
    unsigned w = __shfl_xor(v, o);
    v = w > v ? w : v;
  }
  return v;
}

// ============================ PASS 1 =====================================
// One block per row-quarter: partial sums + candidate (key,val) lists.
extern "C" __global__ __launch_bounds__(BLOCK, 6)
void part_kernel(const float* __restrict__ up, const float* __restrict__ down,
                 const float* __restrict__ yt, const int* __restrict__ masks,
                 float* __restrict__ ws_sums, float2* __restrict__ ws_top,
                 float2* __restrict__ ws_bot) {
  __shared__ float red_f[7][NWAVES];     // nv, sq, sp, seyy, seyu, aspu, aspd
  __shared__ unsigned t1w_t[NWAVES], t1w_b[NWAVES];
  __shared__ unsigned keys_t[CAP]; __shared__ float vals_t[CAP];
  __shared__ unsigned keys_b[CAP]; __shared__ float vals_b[CAP];
  __shared__ int ct, cb;

  const int tid = threadIdx.x;
  const int lane = tid & 63;
  const int wv = tid >> 6;
  const int bq = blockIdx.x;
  const int row = bq >> 2;
  const int q = bq & 3;
  const int s = q * QF4;
  const int e = (s + QF4) < NF4 ? (s + QF4) : NF4;
  const int cnt = e - s;                 // 313,313,313,311
  const long long b4 = (long long)row * NF4 + s;

  if (tid == 0) { ct = 0; cb = 0; }
  if (tid < CAP) {
    keys_t[tid] = 0u; vals_t[tid] = 0.f;
    keys_b[tid] = 0u; vals_b[tid] = 0.f;
  }

  const float4* up4 = (const float4*)up + b4;
  const float4* dn4 = (const float4*)down + b4;
  const float4* yt4 = (const float4*)yt + b4;
  const int4*   mk4 = (const int4*)masks + b4;

  // j=0 is always fully in-range (cnt > 256); j=1 is partial, clamped.
  const int t2 = BLOCK + tid;
  const bool inb2 = t2 < cnt;
  const int f2 = inb2 ? t2 : cnt - 1;
  float4 y0 = yt4[tid], u0 = up4[tid], d0 = dn4[tid];
  float4 y1 = yt4[f2],  u1 = up4[f2],  d1 = dn4[f2];
  int4   m0 = mk4[tid], m1 = mk4[f2];
  __builtin_amdgcn_sched_barrier(0);     // keep all 8 loads issued upfront

  int nv_l = 0;
  float sq = 0.f, sp = 0.f, seyy = 0.f, seyu = 0.f, aspu = 0.f, aspd = 0.f;
  unsigned kk[8]; float ua[8], da[8];
  unsigned tmax = 0u, tbmax = 0u;

#define ELEM(idx, Y, U, D, M, INB)                                      \
  {                                                                     \
    const bool valid = (INB) && ((M) > 0);                              \
    const float y = (Y), u = (U), d = (D);                              \
    const unsigned kd = valid ? mono_f32(y) : 0u;                       \
    const unsigned kb = valid ? ~kd : 0u;                               \
    kk[idx] = kd; ua[idx] = u; da[idx] = d;                             \
    tmax = kd > tmax ? kd : tmax;                                       \
    tbmax = kb > tbmax ? kb : tbmax;                                    \
    if (valid) {                                                        \
      nv_l++;                                                           \
      const float ey = __expf(y);                                       \
      const float eu = __expf(u);                                       \
      const float ed = __expf(d);                                       \
      sq += ey; seyy += ey * y; seyu += ey * u; sp += eu;               \
      aspu += (u > 15.f) ? u : __logf(1.f + eu);                        \
      aspd += (d > 15.f) ? d : __logf(1.f + ed);                        \
    }                                                                   \
  }

  ELEM(0, y0.x, u0.x, d0.x, m0.x, true)
  ELEM(1, y0.y, u0.y, d0.y, m0.y, true)
  ELEM(2, y0.z, u0.z, d0.z, m0.z, true)
  ELEM(3, y0.w, u0.w, d0.w, m0.w, true)
  ELEM(4, y1.x, u1.x, d1.x, m1.x, inb2)
  ELEM(5, y1.y, u1.y, d1.y, m1.y, inb2)
  ELEM(6, y1.z, u1.z, d1.z, m1.z, inb2)
  ELEM(7, y1.w, u1.w, d1.w, m1.w, inb2)
#undef ELEM

  // Wave reduces of scalars.
  nv_l = wave_sum_i(nv_l);
  sq = wave_sum_f(sq);
  sp = wave_sum_f(sp);
  seyy = wave_sum_f(seyy);
  seyu = wave_sum_f(seyu);
  aspu = wave_sum_f(aspu);
  aspd = wave_sum_f(aspd);
  if (lane == 0) {
    red_f[0][wv] = (float)nv_l;
    red_f[1][wv] = sq;  red_f[2][wv] = sp;
    red_f[3][wv] = seyy; red_f[4][wv] = seyu;
    red_f[5][wv] = aspu; red_f[6][wv] = aspd;
  }

  // Per-wave candidate thresholds, TR rounds (top & bottom interleaved).
  // min over waves of (TR-th largest thread-max) guarantees >= NWAVES*TR=12
  // >= TOPKK elements >= t_q, so t_q <= quarter's 10th largest key.
  {
    unsigned vt = tmax, vb = tbmax, t1t = 0u, t1b = 0u;
#pragma unroll
    for (int r = 0; r < TR; ++r) {
      unsigned mt = wave_max_u(vt);
      unsigned mb = wave_max_u(vb);
      if (vt == mt) vt = 0u;
      if (vb == mb) vb = 0u;
      t1t = mt; t1b = mb;
    }
    if (lane == 0) { t1w_t[wv] = t1t; t1w_b[wv] = t1b; }
  }
  __syncthreads();

  unsigned tq_t = 0xFFFFFFFFu, tq_b = 0xFFFFFFFFu;
#pragma unroll
  for (int w = 0; w < NWAVES; ++w) {
    tq_t = t1w_t[w] < tq_t ? t1w_t[w] : tq_t;
    tq_b = t1w_b[w] < tq_b ? t1w_b[w] : tq_b;
  }

  if (tid < 7) {
    float sm = red_f[tid][0] + red_f[tid][1] + red_f[tid][2] + red_f[tid][3];
    ws_sums[bq * 8 + tid] = sm;
  }

  // Compact candidates (carry their u/d values; column never needed again).
#pragma unroll
  for (int i = 0; i < 8; ++i) {
    const unsigned kd = kk[i];
    if (kd != 0u) {
      if (kd >= tq_t) {
        int p = atomicAdd(&ct, 1);
        if (p < CAP) { keys_t[p] = kd; vals_t[p] = ua[i]; }
      }
      const unsigned kb = ~kd;
      if (kb >= tq_b) {
        int p = atomicAdd(&cb, 1);
        if (p < CAP) { keys_b[p] = kb; vals_b[p] = da[i]; }
      }
    }
  }
  __syncthreads();

  // Padded, coalesced pair writes (unused slots are zero).
  if (tid < CAP) {
    ws_top[bq * CAP + tid] = make_float2(__uint_as_float(keys_t[tid]), vals_t[tid]);
  } else if (tid < 2 * CAP) {
    const int i = tid - CAP;
    ws_bot[bq * CAP + i] = make_float2(__uint_as_float(keys_b[i]), vals_b[i]);
  }
}

// ============================ PASS 2 =====================================
// One wave per row: merge 4 quarters, exact k-th via ballot search, loss.
extern "C" __global__ __launch_bounds__(256, 4)
void finish_kernel(const float* __restrict__ ws_sums,
                   const float2* __restrict__ ws_top,
                   const float2* __restrict__ ws_bot,
                   float* __restrict__ out, int nrows, float inv_nrows) {
  __shared__ float wl[NWAVES];
  const int tid = threadIdx.x;
  const int lane = tid & 63;
  const int wv = tid >> 6;
  const int row = blockIdx.x * NWAVES + wv;

  float loss = 0.f;
  if (row < nrows) {
    // Fold the 4 quarters' 8 partial sums: lane l<32 loads (q=l>>3, i=l&7);
    // xor-fold over bit3 (q lo) and bit4 (q hi) leaves S_i in lane i.
    float v = 0.f;
    if (lane < 32) v = ws_sums[(row * QBLK + (lane >> 3)) * 8 + (lane & 7)];
    v += __shfl_xor(v, 8);
    v += __shfl_xor(v, 16);
    const float nvf = __shfl(v, 0);
    const int nv = (int)nvf;
    if (nv > 0) {
      const int k = nv < TOPKK ? nv : TOPKK;
      const int cb0 = row * QBLK * CAP;     // 256 padded slots per path
      unsigned kt[4], kb[4]; float vt[4], vb[4];
#pragma unroll
      for (int t = 0; t < 4; ++t) {
        const float2 a = ws_top[cb0 + t * 64 + lane];
        const float2 b = ws_bot[cb0 + t * 64 + lane];
        kt[t] = __float_as_uint(a.x); vt[t] = a.y;
        kb[t] = __float_as_uint(b.x); vb[t] = b.y;
      }
      unsigned thr_t = 0u, thr_b = 0u;
#pragma unroll
      for (int b = 31; b >= 0; --b) {
        const unsigned tt = thr_t | (1u << b);
        const unsigned tb = thr_b | (1u << b);
        int c1 = 0, c2 = 0;
#pragma unroll
        for (int t = 0; t < 4; ++t) {
          c1 += __popcll(__ballot(kt[t] >= tt));
          c2 += __popcll(__ballot(kb[t] >= tb));
        }
        thr_t = (c1 >= k) ? tt : thr_t;
        thr_b = (c2 >= k) ? tb : thr_b;
      }
      float su = 0.f, sd = 0.f;
#pragma unroll
      for (int t = 0; t < 4; ++t) {
        if (kt[t] >= thr_t && kt[t] != 0u) su += vt[t];
        if (kb[t] >= thr_b && kb[t] != 0u) sd += vb[t];
      }
      su = wave_sum_f(su);
      sd = wave_sum_f(sd);
      const float SQ  = __shfl(v, 1), SP  = __shfl(v, 2);
      const float SYY = __shfl(v, 3), SYU = __shfl(v, 4);
      const float ASU = __shfl(v, 5), ASD = __shfl(v, 6);
      // KL closed form: sum q*(logq-logp) = (Seyy-Seyu)/Sq - log(Sq) + log(Sp)
      const float kl = (SYY - SYU) / SQ - __logf(SQ) + __logf(SP);
      loss = ((ASU - su) + 0.5f * (ASD - sd) + 0.3f * kl) / nvf;
    }
  }
  if (lane == 0) wl[wv] = loss;
  __syncthreads();
  if (tid == 0) {
    atomicAdd(out, (wl[0] + wl[1] + wl[2] + wl[3]) * inv_nrows);
  }
}

extern "C" void kernel_launch(void* const* d_in, const int* in_sizes, int n_in,
                              void* d_out, int out_size, void* d_ws, size_t ws_size,
                              hipStream_t stream) {
  const float* up_logits   = (const float*)d_in[0];
  const float* down_logits = (const float*)d_in[1];
  const float* y_true      = (const float*)d_in[2];
  const int*   masks       = (const int*)d_in[3];

  const int nrows = in_sizes[0] / NCOLS;
  const int nrq = nrows * QBLK;
  const size_t need = (size_t)nrq * (8 + 4 * CAP) * sizeof(float);

  hipMemsetAsync(d_out, 0, sizeof(float) * (size_t)out_size, stream);

  // Workspace layout (observed ws is 256 MiB; we need ~4.3 MB).
  float* wsf = (float*)d_ws;
  float* ws_sums = wsf;
  float2* ws_top = (float2*)(wsf + (size_t)nrq * 8);
  float2* ws_bot = ws_top + (size_t)nrq * CAP;
  (void)need; (void)ws_size;

  part_kernel<<<nrq, BLOCK, 0, stream>>>(up_logits, down_logits, y_true, masks,
                                         ws_sums, ws_top, ws_bot);
  const int p2blocks = (nrows + NWAVES - 1) / NWAVES;
  finish_kernel<<<p2blocks, 256, 0, stream>>>(ws_sums, ws_top, ws_bot,
                                              (float*)d_out, nrows,
                                              1.0f / (float)nrows);
}

// Round 5
// 119.027 us; speedup vs baseline: 1.0484x; 1.0484x over previous
//
#include <hip/hip_runtime.h>
#include <math.h>

#define NCOLS 5000
#define NF4   1250            // NCOLS / 4
#define BLOCK 1024
#define NWAVES 16             // BLOCK / 64
#define T2    (NF4 - BLOCK)   // 226 threads have a second element
#define TOPKK 10
#define CAP   256             // candidate capacity per path (expect ~30-60)

// Monotone-ascending mapping float -> uint32 (total order on finite floats).
__device__ __forceinline__ unsigned mono_f32(float f) {
  unsigned u = __float_as_uint(f);
  return (u & 0x80000000u) ? ~u : (u | 0x80000000u);
}

__device__ __forceinline__ float wave_sum_f(float v) {
#pragma unroll
  for (int o = 1; o < 64; o <<= 1) v += __shfl_xor(v, o);
  return v;
}
__device__ __forceinline__ int wave_sum_i(int v) {
#pragma unroll
  for (int o = 1; o < 64; o <<= 1) v += __shfl_xor(v, o);
  return v;
}
__device__ __forceinline__ unsigned wave_max_u(unsigned v) {
#pragma unroll
  for (int o = 1; o < 64; o <<= 1) {
    unsigned w = __shfl_xor(v, o);
    v = w > v ? w : v;
  }
  return v;
}

// 1024-thread block per row: 2 float4 batches/thread (32 payload VGPRs),
// keys staged to LDS, launch_bounds(1024,8) -> 2 blocks/CU = 32 waves/CU
// (chip max; 2x the previous 16). TR=1 threshold: min over the 16 per-wave
// maxes guarantees >= 16 >= k candidates above threshold.
extern "C" __global__ __launch_bounds__(BLOCK, 8)
void row_loss_kernel(const float* __restrict__ up, const float* __restrict__ down,
                     const float* __restrict__ yt, const int* __restrict__ masks,
                     float* __restrict__ ws) {
  __shared__ uint4 km_s[NF4];          // 20 KB: per-element keys
  __shared__ float red_f[6][NWAVES];   // sq, sp, seyy, seyu, aspu, aspd
  __shared__ int red_i[NWAVES];        // nv partials
  __shared__ unsigned t1w_t[NWAVES];   // per-wave max key (top)
  __shared__ unsigned t1w_b[NWAVES];   // per-wave max key (bottom, ~key)
  __shared__ unsigned keys_t[CAP]; __shared__ int col_t[CAP];
  __shared__ unsigned keys_b[CAP]; __shared__ int col_b[CAP];
  __shared__ int ct, cb;
  __shared__ float s_res[2];           // SU, SD

  const int tid = threadIdx.x;
  const int lane = tid & 63;
  const int wv = tid >> 6;
  const int row = blockIdx.x;
  const long long b4 = (long long)row * NF4;
  const long long base = (long long)row * NCOLS;

  if (tid == 0) { ct = 0; cb = 0; }

  const float4* up4 = (const float4*)up + b4;
  const float4* dn4 = (const float4*)down + b4;
  const float4* yt4 = (const float4*)yt + b4;
  const int4*   mk4 = (const int4*)masks + b4;

  const bool inb2 = tid < T2;
  const int f2 = inb2 ? BLOCK + tid : NF4 - 1;   // clamp, no branch

  // ---- 8 vector loads, all issued upfront (32 payload VGPRs).
  float4 y0 = yt4[tid], u0 = up4[tid], d0 = dn4[tid];
  int4   m0 = mk4[tid];
  float4 y1 = yt4[f2],  u1 = up4[f2],  d1 = dn4[f2];
  int4   m1 = mk4[f2];
  __builtin_amdgcn_sched_barrier(0);   // don't sink loads into compute

  int nv_l = 0;
  float sq = 0.f, sp = 0.f, seyy = 0.f, seyu = 0.f, aspu = 0.f, aspd = 0.f;
  unsigned tmax = 0u, tbmax = 0u;
  unsigned kk[4];

#define ELEM(idx, Y, U, D, M, INB)                                      \
  {                                                                     \
    const bool valid = (INB) && ((M) > 0);                              \
    const float y = (Y), u = (U), d = (D);                              \
    const unsigned kd = valid ? mono_f32(y) : 0u;                       \
    const unsigned kb = valid ? ~kd : 0u;                               \
    kk[idx] = kd;                                                       \
    tmax = kd > tmax ? kd : tmax;                                       \
    tbmax = kb > tbmax ? kb : tbmax;                                    \
    if (valid) {                                                        \
      nv_l++;                                                           \
      const float ey = __expf(y);                                      \
      const float eu = __expf(u);                                      \
      const float ed = __expf(d);                                      \
      sq += ey; seyy += ey * y; seyu += ey * u; sp += eu;               \
      aspu += (u > 15.f) ? u : __logf(1.f + eu);                       \
      aspd += (d > 15.f) ? d : __logf(1.f + ed);                       \
    }                                                                   \
  }

  ELEM(0, y0.x, u0.x, d0.x, m0.x, true)
  ELEM(1, y0.y, u0.y, d0.y, m0.y, true)
  ELEM(2, y0.z, u0.z, d0.z, m0.z, true)
  ELEM(3, y0.w, u0.w, d0.w, m0.w, true)
  km_s[tid] = make_uint4(kk[0], kk[1], kk[2], kk[3]);
  ELEM(0, y1.x, u1.x, d1.x, m1.x, inb2)
  ELEM(1, y1.y, u1.y, d1.y, m1.y, inb2)
  ELEM(2, y1.z, u1.z, d1.z, m1.z, inb2)
  ELEM(3, y1.w, u1.w, d1.w, m1.w, inb2)
  if (inb2) km_s[BLOCK + tid] = make_uint4(kk[0], kk[1], kk[2], kk[3]);
#undef ELEM

  // ---- Wave reduces of scalars + per-wave max keys (TR=1).
  nv_l = wave_sum_i(nv_l);
  sq = wave_sum_f(sq);
  sp = wave_sum_f(sp);
  seyy = wave_sum_f(seyy);
  seyu = wave_sum_f(seyu);
  aspu = wave_sum_f(aspu);
  aspd = wave_sum_f(aspd);
  const unsigned wmax_t = wave_max_u(tmax);
  const unsigned wmax_b = wave_max_u(tbmax);
  if (lane == 0) {
    red_i[wv] = nv_l;
    red_f[0][wv] = sq;  red_f[1][wv] = sp;
    red_f[2][wv] = seyy; red_f[3][wv] = seyu;
    red_f[4][wv] = aspu; red_f[5][wv] = aspd;
    t1w_t[wv] = wmax_t;
    t1w_b[wv] = wmax_b;
  }
  __syncthreads();

  int nv = 0;
#pragma unroll
  for (int w = 0; w < NWAVES; ++w) nv += red_i[w];
  const int k = nv < TOPKK ? nv : TOPKK;

  // Threshold = min over nonzero per-wave maxes: each of the 16 waves owns
  // >= 1 element >= t, so >= 16 >= k candidates survive the filter.
  unsigned t1 = 0xFFFFFFFFu, t1b = 0xFFFFFFFFu;
#pragma unroll
  for (int w = 0; w < NWAVES; ++w) {
    const unsigned a = t1w_t[w], b = t1w_b[w];
    if (a != 0u && a < t1) t1 = a;
    if (b != 0u && b < t1b) t1b = b;
  }

  // ---- Compact candidate (key, column) pairs into LDS.
  {
    const uint4 c0 = km_s[tid];
    const unsigned ka[4] = {c0.x, c0.y, c0.z, c0.w};
#pragma unroll
    for (int c = 0; c < 4; ++c) {
      const unsigned kd = ka[c];
      if (kd != 0u) {
        if (kd >= t1) {
          int i = atomicAdd(&ct, 1);
          if (i < CAP) { keys_t[i] = kd; col_t[i] = (tid << 2) + c; }
        }
        const unsigned kb = ~kd;
        if (kb >= t1b) {
          int i = atomicAdd(&cb, 1);
          if (i < CAP) { keys_b[i] = kb; col_b[i] = (tid << 2) + c; }
        }
      }
    }
  }
  if (inb2) {
    const uint4 c1 = km_s[BLOCK + tid];
    const unsigned ka[4] = {c1.x, c1.y, c1.z, c1.w};
#pragma unroll
    for (int c = 0; c < 4; ++c) {
      const unsigned kd = ka[c];
      if (kd != 0u) {
        if (kd >= t1) {
          int i = atomicAdd(&ct, 1);
          if (i < CAP) { keys_t[i] = kd; col_t[i] = ((BLOCK + tid) << 2) + c; }
        }
        const unsigned kb = ~kd;
        if (kb >= t1b) {
          int i = atomicAdd(&cb, 1);
          if (i < CAP) { keys_b[i] = kb; col_b[i] = ((BLOCK + tid) << 2) + c; }
        }
      }
    }
  }
  __syncthreads();

  // ---- Waves 0/1: exact k-th key via 32-step ballot binary search,
  //      then sum of u/d over the selected top-k (L2-warm reload).
  if (wv == 0) {
    const int n = ct < CAP ? ct : CAP;
    unsigned kc[4];
#pragma unroll
    for (int t = 0; t < 4; ++t)
      kc[t] = (t * 64 + lane < n) ? keys_t[t * 64 + lane] : 0u;
    unsigned thr = 0u;
#pragma unroll
    for (int b = 31; b >= 0; --b) {
      const unsigned t = thr | (1u << b);
      int c = 0;
#pragma unroll
      for (int q = 0; q < 4; ++q) c += __popcll(__ballot(kc[q] >= t));
      thr = (c >= k) ? t : thr;
    }
    float su = 0.f;
#pragma unroll
    for (int t = 0; t < 4; ++t)
      if (kc[t] >= thr && kc[t] != 0u) su += up[base + col_t[t * 64 + lane]];
    su = wave_sum_f(su);
    if (lane == 0) s_res[0] = su;
  } else if (wv == 1) {
    const int n = cb < CAP ? cb : CAP;
    unsigned kc[4];
#pragma unroll
    for (int t = 0; t < 4; ++t)
      kc[t] = (t * 64 + lane < n) ? keys_b[t * 64 + lane] : 0u;
    unsigned thr = 0u;
#pragma unroll
    for (int b = 31; b >= 0; --b) {
      const unsigned t = thr | (1u << b);
      int c = 0;
#pragma unroll
      for (int q = 0; q < 4; ++q) c += __popcll(__ballot(kc[q] >= t));
      thr = (c >= k) ? t : thr;
    }
    float sd = 0.f;
#pragma unroll
    for (int t = 0; t < 4; ++t)
      if (kc[t] >= thr && kc[t] != 0u) sd += down[base + col_b[t * 64 + lane]];
    sd = wave_sum_f(sd);
    if (lane == 0) s_res[1] = sd;
  }
  __syncthreads();

  if (tid == 0) {
    float loss = 0.f;
    if (nv > 0) {
      float SQ = 0.f, SP = 0.f, SYY = 0.f, SYU = 0.f, ASU = 0.f, ASD = 0.f;
#pragma unroll
      for (int w = 0; w < NWAVES; ++w) {
        SQ += red_f[0][w]; SP += red_f[1][w];
        SYY += red_f[2][w]; SYU += red_f[3][w];
        ASU += red_f[4][w]; ASD += red_f[5][w];
      }
      const float SU = s_res[0];
      const float SD = s_res[1];
      // KL closed form: sum q*(logq-logp) = (Seyy-Seyu)/Sq - log(Sq) + log(Sp)
      const float kl = (SYY - SYU) / SQ - __logf(SQ) + __logf(SP);
      const float up_loss = ASU - SU;  // sum softplus(u) - sum_{topk} u
      const float dn_loss = ASD - SD;  // sum softplus(d) - sum_{botk} d
      loss = (up_loss + 0.5f * dn_loss + 0.3f * kl) / (float)nv;
    }
    ws[row] = loss;                    // plain store; reducer sums
  }
}

// Deterministic 1-block tree reduction of the per-row losses.
extern "C" __global__ __launch_bounds__(256)
void reduce_loss_kernel(const float* __restrict__ ws, float* __restrict__ out,
                        int n, float inv_n) {
  __shared__ float part[4];
  const int tid = threadIdx.x;
  const int lane = tid & 63;
  const int wv = tid >> 6;
  float s = 0.f;
  const int n4 = n >> 2;
  const float4* w4 = (const float4*)ws;
  for (int i = tid; i < n4; i += 256) {
    const float4 v = w4[i];
    s += (v.x + v.y) + (v.z + v.w);
  }
  for (int i = (n4 << 2) + tid; i < n; i += 256) s += ws[i];
  s = wave_sum_f(s);
  if (lane == 0) part[wv] = s;
  __syncthreads();
  if (tid == 0) out[0] = (part[0] + part[1] + part[2] + part[3]) * inv_n;
}

extern "C" void kernel_launch(void* const* d_in, const int* in_sizes, int n_in,
                              void* d_out, int out_size, void* d_ws, size_t ws_size,
                              hipStream_t stream) {
  const float* up_logits   = (const float*)d_in[0];
  const float* down_logits = (const float*)d_in[1];
  const float* y_true      = (const float*)d_in[2];
  const int*   masks       = (const int*)d_in[3];

  const int nrows = in_sizes[0] / NCOLS;

  row_loss_kernel<<<nrows, BLOCK, 0, stream>>>(up_logits, down_logits, y_true,
                                               masks, (float*)d_ws);
  reduce_loss_kernel<<<1, 256, 0, stream>>>((const float*)d_ws, (float*)d_out,
                                            nrows, 1.0f / (float)nrows);
}